// Round 4
// baseline (162.762 us; speedup 1.0000x reference)
//
#include <hip/hip_runtime.h>
#include <math.h>

// [SQ, B, NP, HN] fp32, unscaled QK^T softmax attention.
#define SQ 2048
#define NBH 32           // B*NP heads
#define HN 64
#define BQ 128           // queries per block (4 waves x 32)
#define BK 64            // keys per tile
#define NT (SQ/BK)       // 32 key tiles
#define TOK 2048         // floats between consecutive tokens (B*NP*HN)
#define LDK 72           // padded LDS leading dim (144 B, 16B-divisible)

typedef _Float16 half2v __attribute__((ext_vector_type(2)));
typedef _Float16 half4v __attribute__((ext_vector_type(4)));
typedef _Float16 half8v __attribute__((ext_vector_type(8)));
typedef float f32x16 __attribute__((ext_vector_type(16)));

// Double-buffered flash attention, S^T = K.Q^T via mfma_32x32x16_f16.
// 32x32 C layout: col = lane&31, row = (reg&3)+8*(reg>>2)+4*(lane>>5)
// => softmax state per-lane uniform; one shfl_xor(32) completes reductions.
// PV uses permuted k-order pi so P^T stays in registers (no LDS roundtrip).

__device__ __forceinline__
void load_stage(const float* __restrict__ K, const float* __restrict__ V,
                int kt, size_t hoff, int t, float4 kr[4], float4 vr[4]) {
  const int key = t >> 2, qq = t & 3;
  const float* kp = K + (size_t)(kt + key) * TOK + hoff;
  #pragma unroll
  for (int i = 0; i < 4; ++i)
    kr[i] = *(const float4*)(kp + qq * 4 + i * 16);
  const int kp2 = (t >> 3) * 2, m = t & 7, db = m * 8;
  const float* v0 = V + (size_t)(kt + kp2) * TOK + hoff + db;
  vr[0] = *(const float4*)v0;
  vr[1] = *(const float4*)(v0 + 4);
  vr[2] = *(const float4*)(v0 + TOK);
  vr[3] = *(const float4*)(v0 + TOK + 4);
}

__device__ __forceinline__
void write_stage(_Float16 (*kb)[LDK], _Float16 (*vt)[LDK], int t,
                 const float4 kr[4], const float4 vr[4]) {
  const int key = t >> 2, qq = t & 3;
  #pragma unroll
  for (int i = 0; i < 4; ++i) {
    const int d = qq * 4 + i * 16;
    half4v h;
    h[0] = (_Float16)kr[i].x; h[1] = (_Float16)kr[i].y;
    h[2] = (_Float16)kr[i].z; h[3] = (_Float16)kr[i].w;
    *(half4v*)&kb[key][d] = h;
  }
  const int kp2 = (t >> 3) * 2, m = t & 7, db = m * 8;
  const int keyS = kp2 ^ (m << 3);   // xor-swizzle: (dim>>3)&7 == m here
  const float av[8] = {vr[0].x, vr[0].y, vr[0].z, vr[0].w,
                       vr[1].x, vr[1].y, vr[1].z, vr[1].w};
  const float bv[8] = {vr[2].x, vr[2].y, vr[2].z, vr[2].w,
                       vr[3].x, vr[3].y, vr[3].z, vr[3].w};
  #pragma unroll
  for (int j = 0; j < 8; ++j) {
    half2v h; h[0] = (_Float16)av[j]; h[1] = (_Float16)bv[j];
    *(half2v*)&vt[db + j][keyS] = h;
  }
}

__global__ __launch_bounds__(256, 3)
void fattn_mfma(const float* __restrict__ Q, const float* __restrict__ K,
                const float* __restrict__ V, float* __restrict__ O) {
  __shared__ __align__(16) _Float16 kb[2][BK][LDK];  // [buf][key][dim]
  __shared__ __align__(16) _Float16 vt[2][HN][LDK];  // [buf][dim][key], swizzled

  const int t = threadIdx.x;
  const int lane = t & 63;
  const int w = t >> 6;
  const int h2 = lane >> 5;
  const int l31 = lane & 31;
  const int q0 = blockIdx.x * BQ + w * 32;
  const size_t hoff = (size_t)blockIdx.y * HN;

  // ---- Q B-fragments, registers all kernel: n=query=l31, k=dim=8*h2+j+16*ks ----
  half8v qf[4];
  {
    const float* qp = Q + (size_t)(q0 + l31) * TOK + hoff + 8 * h2;
    #pragma unroll
    for (int ks = 0; ks < 4; ++ks) {
      float4 a = *(const float4*)(qp + 16 * ks);
      float4 b = *(const float4*)(qp + 16 * ks + 4);
      half8v f;
      f[0] = (_Float16)a.x; f[1] = (_Float16)a.y; f[2] = (_Float16)a.z; f[3] = (_Float16)a.w;
      f[4] = (_Float16)b.x; f[5] = (_Float16)b.y; f[6] = (_Float16)b.z; f[7] = (_Float16)b.w;
      qf[ks] = f;
    }
  }

  f32x16 acc0, acc1;   // O^T frags: dims 0..31, 32..63
  #pragma unroll
  for (int r = 0; r < 16; ++r) { acc0[r] = 0.f; acc1[r] = 0.f; }
  float m_i = -INFINITY, l_i = 0.f;

  float4 kr[4], vr[4];
  load_stage(K, V, 0, hoff, t, kr, vr);
  write_stage(kb[0], vt[0], t, kr, vr);
  __syncthreads();

  for (int it = 0; it < NT; ++it) {
    const int cur = it & 1;
    if (it + 1 < NT)
      load_stage(K, V, (it + 1) * BK, hoff, t, kr, vr);  // overlaps compute below

    // ---- S^T = K . Q^T ----
    f32x16 sf0, sf1;
    {
      f32x16 c0, c1;
      #pragma unroll
      for (int r = 0; r < 16; ++r) { c0[r] = 0.f; c1[r] = 0.f; }
      #pragma unroll
      for (int ks = 0; ks < 4; ++ks) {
        half8v a0v = *(const half8v*)&kb[cur][l31][8 * h2 + 16 * ks];
        half8v a1v = *(const half8v*)&kb[cur][l31 + 32][8 * h2 + 16 * ks];
        c0 = __builtin_amdgcn_mfma_f32_32x32x16_f16(a0v, qf[ks], c0, 0, 0, 0);
        c1 = __builtin_amdgcn_mfma_f32_32x32x16_f16(a1v, qf[ks], c1, 0, 0, 0);
      }
      sf0 = c0; sf1 = c1;
    }

    // ---- online softmax (query = l31; lane^32 holds the other 32 keys) ----
    float mx = -INFINITY;
    #pragma unroll
    for (int r = 0; r < 16; ++r) mx = fmaxf(mx, fmaxf(sf0[r], sf1[r]));
    mx = fmaxf(mx, __shfl_xor(mx, 32, 64));
    const float mnew = fmaxf(m_i, mx);
    const float alpha = __expf(m_i - mnew);   // 0 on first tile
    float rsum = 0.f;
    #pragma unroll
    for (int r = 0; r < 16; ++r) {
      float p0 = __expf(sf0[r] - mnew);
      float p1 = __expf(sf1[r] - mnew);
      sf0[r] = p0; sf1[r] = p1;
      rsum += p0 + p1;
    }
    rsum += __shfl_xor(rsum, 32, 64);
    l_i = l_i * alpha + rsum;
    m_i = mnew;
    #pragma unroll
    for (int r = 0; r < 16; ++r) { acc0[r] *= alpha; acc1[r] *= alpha; }

    // ---- PV: O^T += V^T . P^T, permuted k-order; P^T = C-layout regs packed ----
    #pragma unroll
    for (int ks = 0; ks < 4; ++ks) {
      const int rb = 8 * (ks & 1);
      const f32x16& s = (ks < 2) ? sf0 : sf1;
      union { half8v v8; half2v v2[4]; } pu;
      #pragma unroll
      for (int tt = 0; tt < 4; ++tt) {
        auto pk = __builtin_amdgcn_cvt_pkrtz(s[rb + 2 * tt], s[rb + 2 * tt + 1]);
        pu.v2[tt] = *(half2v*)&pk;
      }
      #pragma unroll
      for (int mbd = 0; mbd < 2; ++mbd) {
        const int dim = l31 + 32 * mbd;
        const int swz = (dim >> 3) & 7;
        union { half8v v8; half4v v4[2]; } au;
        au.v4[0] = *(const half4v*)&vt[cur][dim][(((2 * ks)     ^ swz) * 8) + 4 * h2];
        au.v4[1] = *(const half4v*)&vt[cur][dim][(((2 * ks + 1) ^ swz) * 8) + 4 * h2];
        if (mbd == 0)
          acc0 = __builtin_amdgcn_mfma_f32_32x32x16_f16(au.v8, pu.v8, acc0, 0, 0, 0);
        else
          acc1 = __builtin_amdgcn_mfma_f32_32x32x16_f16(au.v8, pu.v8, acc1, 0, 0, 0);
      }
    }

    if (it + 1 < NT) {
      __syncthreads();                              // all waves done reading buf cur^1
      write_stage(kb[cur ^ 1], vt[cur ^ 1], t, kr, vr);
      __syncthreads();                              // staged data visible
    }
  }

  // ---- epilogue: O^T C-layout -> global; dim = (r&3)+8*(r>>2)+4*h2 (+32) ----
  const float invl = 1.f / l_i;
  float* orow = O + (size_t)(q0 + l31) * TOK + hoff;
  #pragma unroll
  for (int r = 0; r < 16; ++r) {
    const int d = (r & 3) + 8 * (r >> 2) + 4 * h2;
    orow[d]      = acc0[r] * invl;
    orow[d + 32] = acc1[r] * invl;
  }
}

extern "C" void kernel_launch(void* const* d_in, const int* in_sizes, int n_in,
                              void* d_out, int out_size, void* d_ws, size_t ws_size,
                              hipStream_t stream) {
  const float* Q = (const float*)d_in[0];
  const float* K = (const float*)d_in[1];
  const float* V = (const float*)d_in[2];
  float* O = (float*)d_out;
  dim3 grid(SQ / BQ, NBH);   // 16 x 32 = 512 blocks
  dim3 block(256);
  fattn_mfma<<<grid, block, 0, stream>>>(Q, K, V, O);
}